// Round 7
// baseline (1621.853 us; speedup 1.0000x reference)
//
#include <hip/hip_runtime.h>
#include <hip/hip_bf16.h>

typedef __bf16 bf16_t;
typedef __bf16 bf16x4 __attribute__((ext_vector_type(4)));
typedef __bf16 bf16x8 __attribute__((ext_vector_type(8)));
typedef float  f32x4  __attribute__((ext_vector_type(4)));

#define NH    6
#define CH    192
#define HW    112
#define SHIFT 3

// LDS strides (bf16 elems). XLD=200 -> 400B rows; ULD=72 -> 144B rows.
#define XLD 200
#define ULD 72

#define X_OFF   0
#define T_OFF   (64 * XLD)            // 12800
#define VOT_OFF T_OFF                 // VOt [192][72]=13824 overlays dead T
#define P_OFF   (T_OFF + 192 * ULD)   // 26624; P [64][72]=4608
#define LDS_ELEMS (P_OFF + 64 * ULD)  // 31232
#define EXCH_BYTES (LDS_ELEMS * 2)    // 62464: float[2][64][2] = 1024 B
#define LDS_BYTES (EXCH_BYTES + 1024) // 63488 B -> 2 blocks/CU

// ws: Gt (NH*CH*CH bf16) | U^T (NH*CH*CH bf16) | bu f32[NH*CH] | w1 f32[NH*CH]
#define U_OFF_ELEMS  (NH * CH * CH)
#define BU_OFF_BYTES (2 * NH * CH * CH * 2)
#define W1_OFF_BYTES (BU_OFF_BYTES + NH * CH * 4)

// ---- prep: Gt[h][c'][c] = sum_d Wk[c',h,d] * Wq[c,h,d]  (= Wk Wq^T) -------
__global__ void prep_gt(const float* __restrict__ Wq, const float* __restrict__ Wk,
                        bf16_t* __restrict__ gt) {
  __shared__ float wk_row[CH];
  int h = blockIdx.x / CH, cp = blockIdx.x % CH;
  int c = threadIdx.x;
  wk_row[c] = Wk[(cp * NH + h) * CH + c];
  __syncthreads();
  float acc = 0.f;
  for (int d = 0; d < CH; ++d)
    acc += wk_row[d] * Wq[(c * NH + h) * CH + d];
  gt[(h * CH + cp) * CH + c] = (bf16_t)acc;
}

// ---- prep: U^h = Wv^h x Wo^h, stored U^T[c_out][c_in] ----------------------
__global__ void prep_u(const float* __restrict__ Wv, const float* __restrict__ Wo,
                       bf16_t* __restrict__ u_out) {
  __shared__ float wv_row[CH];
  int h = blockIdx.x / CH, ci = blockIdx.x % CH;
  int t = threadIdx.x;
  wv_row[t] = Wv[(ci * NH + h) * CH + t];
  __syncthreads();
  float acc = 0.f;
  for (int d = 0; d < CH; ++d)
    acc += wv_row[d] * Wo[(h * CH + d) * CH + t];
  u_out[(h * CH + t) * CH + ci] = (bf16_t)acc;
}

// ---- prep: bu^h = bv^h x Wo^h ---------------------------------------------
__global__ void prep_bu(const float* __restrict__ bv, const float* __restrict__ Wo,
                        float* __restrict__ bu) {
  int h = blockIdx.x, c = threadIdx.x;
  float acc = 0.f;
  for (int d = 0; d < CH; ++d)
    acc += bv[h * CH + d] * Wo[(h * CH + d) * CH + c];
  bu[h * CH + c] = acc;
}

// ---- prep: w1^h[c'] = sum_d Wk[c',h,d] * bq[h,d] ---------------------------
__global__ void prep_w1(const float* __restrict__ Wk, const float* __restrict__ bq,
                        float* __restrict__ w1) {
  int h = blockIdx.x, cp = threadIdx.x;
  float acc = 0.f;
  for (int d = 0; d < CH; ++d)
    acc += Wk[(cp * NH + h) * CH + d] * bq[h * CH + d];
  w1[h * CH + cp] = acc;
}

// ---- fused swin block: one workgroup per 7x7 window, 8 waves, 2 blocks/CU --
__global__ __launch_bounds__(512, 4) void swin_fused(
    const float* __restrict__ x,
    const float* __restrict__ bo,
    const bf16_t* __restrict__ wts,     // Gt | U
    const float* __restrict__ bu, const float* __restrict__ w1,
    float* __restrict__ out) {
  extern __shared__ char smem_raw[];
  bf16_t* lds  = (bf16_t*)smem_raw;
  bf16_t* Xl   = lds + X_OFF;
  bf16_t* Tl   = lds + T_OFF;
  bf16_t* Pl   = lds + P_OFF;
  bf16_t* VOtl = lds + VOT_OFF;
  float*  exch = (float*)(smem_raw + EXCH_BYTES);   // [2][64][2] (max, sum)

  const int tid  = threadIdx.x;
  const int wave = tid >> 6;           // 0..7
  const int lane = tid & 63;
  const int l15  = lane & 15;
  const int lg   = lane >> 4;          // 0..3

  const int blk = blockIdx.x;
  const int b   = blk >> 8;
  const int rem = blk & 255;
  const int wi  = rem >> 4, wj = rem & 15;

  // zero pad rows 49..63 of X and T (T: head-0 garbage containment)
  for (int idx = tid; idx < 15 * 100; idx += 512) {
    int row = 49 + idx / 100, c2 = (idx % 100) * 2;
    *(unsigned int*)&Xl[row * XLD + c2] = 0u;
    *(unsigned int*)&Tl[row * XLD + c2] = 0u;
  }
  // stage window tokens (roll -3,-3 folded into the gather), f32 -> bf16
  for (int idx = tid; idx < 49 * 48; idx += 512) {
    int t = idx / 48, q4 = idx % 48;
    int hs = wi * 7 + t / 7 + SHIFT; if (hs >= HW) hs -= HW;
    int ws2 = wj * 7 + t % 7 + SHIFT; if (ws2 >= HW) ws2 -= HW;
    const float4 v = *(const float4*)&x[(((b * HW + hs) * HW) + ws2) * CH + q4 * 4];
    bf16x4 pk = { (bf16_t)v.x, (bf16_t)v.y, (bf16_t)v.z, (bf16_t)v.w };
    *(bf16x4*)&Xl[t * XLD + q4 * 4] = pk;
  }

  const int it = wave & 3;             // i-tile (S), c-block (T/Y)
  const int jh = wave >> 2;            // j-half (S), half (T i-tiles, VO c-tiles, Y t-tiles)
  const float scale = 0.07216878364870322f;  // 1/sqrt(192)
  f32x4 yacc[3][2] = {};               // persistent output accumulators

  for (int h = 0; h < NH; ++h) {
    __syncthreads();
    // ---- Phase T: T[i][c'] = sum_c X[i,c] Gt[c',c] (+w1). 2 i-subpasses,
    // wave owns c'-tiles it*3..it*3+2, i-tiles jh*2+{0,1}. acc 12 regs.
    {
      const bf16_t* gt = wts + h * CH * CH;
      const float* w1h = w1 + h * CH;
#pragma unroll
      for (int sp = 0; sp < 2; ++sp) {
        const int itile = jh * 2 + sp;
        f32x4 acc[3] = {};
#pragma unroll
        for (int ks = 0; ks < 6; ++ks) {
          bf16x8 bfr = *(const bf16x8*)&Xl[(itile * 16 + l15) * XLD + ks * 32 + lg * 8];
#pragma unroll
          for (int mi = 0; mi < 3; ++mi) {
            bf16x8 af = *(const bf16x8*)&gt[((it * 3 + mi) * 16 + l15) * CH + ks * 32 + lg * 8];
            acc[mi] = __builtin_amdgcn_mfma_f32_16x16x32_bf16(af, bfr, acc[mi], 0, 0, 0);
          }
        }
        int i = itile * 16 + l15;
        if (i < 49) {
#pragma unroll
          for (int mi = 0; mi < 3; ++mi) {
            int cp0 = (it * 3 + mi) * 16 + lg * 4;
            const f32x4 ww = *(const f32x4*)&w1h[cp0];
            bf16x4 pk = { (bf16_t)(acc[mi][0] + ww[0]), (bf16_t)(acc[mi][1] + ww[1]),
                          (bf16_t)(acc[mi][2] + ww[2]), (bf16_t)(acc[mi][3] + ww[3]) };
            *(bf16x4*)&Tl[i * XLD + cp0] = pk;
          }
        }
      }
    }
    __syncthreads();
    // ---- Phase S: S[i,j] = sum_c' X[j,c'] T[i,c']; wave owns i-tile `it`,
    // j-half `jh` (2 j-tiles). sacc 8 regs. Partial softmax + exchange write.
    f32x4 sacc[2] = {};
#pragma unroll
    for (int ks = 0; ks < 6; ++ks) {
      bf16x8 bt = *(const bf16x8*)&Tl[(it * 16 + l15) * XLD + ks * 32 + lg * 8];
#pragma unroll
      for (int jj = 0; jj < 2; ++jj) {
        bf16x8 ax = *(const bf16x8*)&Xl[((jh * 2 + jj) * 16 + l15) * XLD + ks * 32 + lg * 8];
        sacc[jj] = __builtin_amdgcn_mfma_f32_16x16x32_bf16(ax, bt, sacc[jj], 0, 0, 0);
      }
    }
    float mp = -1e30f;
#pragma unroll
    for (int jj = 0; jj < 2; ++jj)
#pragma unroll
      for (int r = 0; r < 4; ++r) {
        int j = (jh * 2 + jj) * 16 + lg * 4 + r;
        if (j < 49) mp = fmaxf(mp, sacc[jj][r]);
      }
    mp = fmaxf(mp, __shfl_xor(mp, 16));
    mp = fmaxf(mp, __shfl_xor(mp, 32));
    float e[2][4];
    float sp_ = 0.f;
#pragma unroll
    for (int jj = 0; jj < 2; ++jj)
#pragma unroll
      for (int r = 0; r < 4; ++r) {
        int j = (jh * 2 + jj) * 16 + lg * 4 + r;
        float v = (j < 49) ? __expf((sacc[jj][r] - mp) * scale) : 0.f;
        e[jj][r] = v;
        sp_ += v;
      }
    sp_ += __shfl_xor(sp_, 16);
    sp_ += __shfl_xor(sp_, 32);
    const int i = it * 16 + l15;
    if (lg == 0) {
      exch[(jh * 64 + i) * 2]     = mp;
      exch[(jh * 64 + i) * 2 + 1] = sp_;
    }
    __syncthreads();
    // ---- Phase C: softmax finish + P write; VO-GEMM + VOt write (over dead T)
    {
      float mo = exch[((1 - jh) * 64 + i) * 2];
      float so = exch[((1 - jh) * 64 + i) * 2 + 1];
      float m  = fmaxf(mp, mo);
      float s  = sp_ * __expf((mp - m) * scale) + so * __expf((mo - m) * scale);
      float f  = __expf((mp - m) * scale) / s;
#pragma unroll
      for (int jj = 0; jj < 2; ++jj) {
        bf16x4 pk = { (bf16_t)(e[jj][0] * f), (bf16_t)(e[jj][1] * f),
                      (bf16_t)(e[jj][2] * f), (bf16_t)(e[jj][3] * f) };
        *(bf16x4*)&Pl[i * ULD + (jh * 2 + jj) * 16 + lg * 4] = pk;
      }
    }
    {
      // VO[c][s] = sum_c X[s,c] U^T[c_out,c] + bu; wave: s-tile `it`, c-tiles jh*6..+5
      const bf16_t* U_h = wts + U_OFF_ELEMS + h * CH * CH;
      const float* bu_h = bu + h * CH;
      f32x4 vacc[6] = {};
#pragma unroll
      for (int ks = 0; ks < 6; ++ks) {
        bf16x8 ax = *(const bf16x8*)&Xl[(it * 16 + l15) * XLD + ks * 32 + lg * 8];
#pragma unroll
        for (int cj = 0; cj < 6; ++cj) {
          bf16x8 bu8 = *(const bf16x8*)&U_h[((jh * 6 + cj) * 16 + l15) * CH + ks * 32 + lg * 8];
          vacc[cj] = __builtin_amdgcn_mfma_f32_16x16x32_bf16(ax, bu8, vacc[cj], 0, 0, 0);
        }
      }
#pragma unroll
      for (int cj = 0; cj < 6; ++cj) {
        int c = (jh * 6 + cj) * 16 + l15;
        float bb = bu_h[c];
        bf16x4 pk = { (bf16_t)(vacc[cj][0] + bb), (bf16_t)(vacc[cj][1] + bb),
                      (bf16_t)(vacc[cj][2] + bb), (bf16_t)(vacc[cj][3] + bb) };
        *(bf16x4*)&VOtl[c * ULD + it * 16 + lg * 4] = pk;
      }
    }
    __syncthreads();
    // ---- Phase Y: yacc[c,t] += sum_s VOt[c,s] P[t,s]
    {
#pragma unroll
      for (int ks = 0; ks < 2; ++ks) {
        bf16x8 af[3], bfr[2];
#pragma unroll
        for (int mi = 0; mi < 3; ++mi)
          af[mi] = *(const bf16x8*)&VOtl[((it * 3 + mi) * 16 + l15) * ULD + ks * 32 + lg * 8];
#pragma unroll
        for (int ni = 0; ni < 2; ++ni)
          bfr[ni] = *(const bf16x8*)&Pl[((jh * 2 + ni) * 16 + l15) * ULD + ks * 32 + lg * 8];
#pragma unroll
        for (int mi = 0; mi < 3; ++mi)
#pragma unroll
          for (int ni = 0; ni < 2; ++ni)
            yacc[mi][ni] = __builtin_amdgcn_mfma_f32_16x16x32_bf16(af[mi], bfr[ni], yacc[mi][ni], 0, 0, 0);
      }
    }
  }

  // ---- epilogue: +bo, plain-reshape merge + roll(+3,+3), packed f32x4 stores
#pragma unroll
  for (int ni = 0; ni < 2; ++ni) {
    int t = (jh * 2 + ni) * 16 + l15;
    if (t < 49) {
      int pos = rem * 49 + t;
      int hp = pos / 112, wp = pos % 112;
      hp += SHIFT; if (hp >= HW) hp -= HW;
      wp += SHIFT; if (wp >= HW) wp -= HW;
      float* op = out + (((b * HW + hp) * HW) + wp) * CH;
#pragma unroll
      for (int mi = 0; mi < 3; ++mi) {
        int c0 = (it * 3 + mi) * 16 + lg * 4;
        f32x4 v = yacc[mi][ni];
        v[0] += bo[c0]; v[1] += bo[c0 + 1]; v[2] += bo[c0 + 2]; v[3] += bo[c0 + 3];
        *(f32x4*)&op[c0] = v;
      }
    }
  }
}

extern "C" void kernel_launch(void* const* d_in, const int* in_sizes, int n_in,
                              void* d_out, int out_size, void* d_ws, size_t ws_size,
                              hipStream_t stream) {
  const float* x  = (const float*)d_in[0];
  const float* Wq = (const float*)d_in[1];
  const float* bq = (const float*)d_in[2];
  const float* Wk = (const float*)d_in[3];
  const float* Wv = (const float*)d_in[5];
  const float* bv = (const float*)d_in[6];
  const float* Wo = (const float*)d_in[7];
  const float* bo = (const float*)d_in[8];
  float* out = (float*)d_out;
  bf16_t* wts = (bf16_t*)d_ws;                        // Gt | U, 884 KB
  float*  bu  = (float*)((char*)d_ws + BU_OFF_BYTES);
  float*  w1  = (float*)((char*)d_ws + W1_OFF_BYTES);

  prep_gt<<<NH * CH, CH, 0, stream>>>(Wq, Wk, wts);
  prep_u<<<NH * CH, CH, 0, stream>>>(Wv, Wo, wts + U_OFF_ELEMS);
  prep_bu<<<NH, CH, 0, stream>>>(bv, Wo, bu);
  prep_w1<<<NH, CH, 0, stream>>>(Wk, bq, w1);

  (void)hipFuncSetAttribute((const void*)swin_fused,
                            hipFuncAttributeMaxDynamicSharedMemorySize, LDS_BYTES);
  swin_fused<<<dim3(4096), dim3(512), LDS_BYTES, stream>>>(x, bo, wts, bu, w1, out);
}

// Round 8
// 672.367 us; speedup vs baseline: 2.4122x; 2.4122x over previous
//
#include <hip/hip_runtime.h>
#include <hip/hip_bf16.h>

typedef __bf16 bf16_t;
typedef __bf16 bf16x4 __attribute__((ext_vector_type(4)));
typedef __bf16 bf16x8 __attribute__((ext_vector_type(8)));
typedef float  f32x4  __attribute__((ext_vector_type(4)));

#define NH    6
#define CH    192
#define HW    112
#define SHIFT 3

// LDS strides (bf16 elems). XLD=200 -> 400B rows; ULD=72 -> 144B rows.
#define XLD 200
#define ULD 72

#define X_OFF   0
#define T_OFF   (64 * XLD)            // 12800
#define P_OFF   T_OFF                 // overlay after S-phase barrier
#define VOT_OFF (T_OFF + 64 * ULD)
#define LDS_ELEMS (VOT_OFF + 192 * ULD)  // 31232
#define LDS_BYTES (LDS_ELEMS * 2)        // 62464 B

// ws: Gt swizzled (NH*CH*CH bf16) | U swizzled (NH*CH*CH bf16) | bu | w1
// Swizzled fragment layout: [h][tile(12)][ks(6)][lane(64)][e(8)] so one wave
// A-fragment load = contiguous 1024 B.
#define U_OFF_ELEMS  (NH * CH * CH)
#define BU_OFF_BYTES (2 * NH * CH * CH * 2)
#define W1_OFF_BYTES (BU_OFF_BYTES + NH * CH * 4)

__device__ __forceinline__ int swz(int h, int tile, int ks, int c_low, int l15) {
  // c_low = c%32 decomposed as lg*8+e at prep time; here used for kernel side only
  return 0;
}

// ---- prep: Gt[h][c'][c] = sum_d Wk[c',h,d] * Wq[c,h,d], written SWIZZLED ---
__global__ void prep_gt(const float* __restrict__ Wq, const float* __restrict__ Wk,
                        bf16_t* __restrict__ gt) {
  __shared__ float wk_row[CH];
  int h = blockIdx.x / CH, cp = blockIdx.x % CH;
  int c = threadIdx.x;
  wk_row[c] = Wk[(cp * NH + h) * CH + c];
  __syncthreads();
  float acc = 0.f;
  for (int d = 0; d < CH; ++d)
    acc += wk_row[d] * Wq[(c * NH + h) * CH + d];
  // element (row=cp, col=c) -> fragment coords
  int tile = cp >> 4, l15 = cp & 15;
  int ks = c >> 5, lg = (c >> 3) & 3, e = c & 7;
  gt[((((h * 12 + tile) * 6 + ks) << 6) + lg * 16 + l15) * 8 + e] = (bf16_t)acc;
}

// ---- prep: U^h = Wv^h x Wo^h, rows c_out, cols c_in, written SWIZZLED ------
__global__ void prep_u(const float* __restrict__ Wv, const float* __restrict__ Wo,
                       bf16_t* __restrict__ u_out) {
  __shared__ float wv_row[CH];
  int h = blockIdx.x / CH, ci = blockIdx.x % CH;
  int t = threadIdx.x;                            // c_out
  wv_row[t] = Wv[(ci * NH + h) * CH + t];
  __syncthreads();
  float acc = 0.f;
  for (int d = 0; d < CH; ++d)
    acc += wv_row[d] * Wo[(h * CH + d) * CH + t];
  int tile = t >> 4, l15 = t & 15;
  int ks = ci >> 5, lg = (ci >> 3) & 3, e = ci & 7;
  u_out[((((h * 12 + tile) * 6 + ks) << 6) + lg * 16 + l15) * 8 + e] = (bf16_t)acc;
}

// ---- prep: bu^h = bv^h x Wo^h ---------------------------------------------
__global__ void prep_bu(const float* __restrict__ bv, const float* __restrict__ Wo,
                        float* __restrict__ bu) {
  int h = blockIdx.x, c = threadIdx.x;
  float acc = 0.f;
  for (int d = 0; d < CH; ++d)
    acc += bv[h * CH + d] * Wo[(h * CH + d) * CH + c];
  bu[h * CH + c] = acc;
}

// ---- prep: w1^h[c'] = sum_d Wk[c',h,d] * bq[h,d] ---------------------------
__global__ void prep_w1(const float* __restrict__ Wk, const float* __restrict__ bq,
                        float* __restrict__ w1) {
  int h = blockIdx.x, cp = threadIdx.x;
  float acc = 0.f;
  for (int d = 0; d < CH; ++d)
    acc += Wk[(cp * NH + h) * CH + d] * bq[h * CH + d];
  w1[h * CH + cp] = acc;
}

// ---- fused swin block: one workgroup per 7x7 window, 8 waves ---------------
__global__ __launch_bounds__(512, 2) void swin_fused(
    const float* __restrict__ x,
    const float* __restrict__ bo,
    const bf16_t* __restrict__ wts,     // Gt | U (both swizzled)
    const float* __restrict__ bu, const float* __restrict__ w1,
    float* __restrict__ out) {
  extern __shared__ char smem_raw[];
  bf16_t* lds  = (bf16_t*)smem_raw;
  bf16_t* Xl   = lds + X_OFF;
  bf16_t* Tl   = lds + T_OFF;
  bf16_t* Pl   = lds + P_OFF;
  bf16_t* VOtl = lds + VOT_OFF;

  const int tid  = threadIdx.x;
  const int wave = tid >> 6;           // 0..7
  const int lane = tid & 63;
  const int l15  = lane & 15;
  const int lg   = lane >> 4;          // 0..3

  const int blk = blockIdx.x;
  const int b   = blk >> 8;
  const int rem = blk & 255;
  const int wi  = rem >> 4, wj = rem & 15;

  // zero pad rows 49..63 of X
  for (int idx = tid; idx < 15 * 100; idx += 512) {
    int row = 49 + idx / 100, c2 = (idx % 100) * 2;
    *(unsigned int*)&Xl[row * XLD + c2] = 0u;
  }
  // stage window tokens (roll -3,-3 folded into the gather), f32 -> bf16
  for (int idx = tid; idx < 49 * 48; idx += 512) {
    int t = idx / 48, q4 = idx % 48;
    int hs = wi * 7 + t / 7 + SHIFT; if (hs >= HW) hs -= HW;
    int ws2 = wj * 7 + t % 7 + SHIFT; if (ws2 >= HW) ws2 -= HW;
    const float4 v = *(const float4*)&x[(((b * HW + hs) * HW) + ws2) * CH + q4 * 4];
    bf16x4 pk = { (bf16_t)v.x, (bf16_t)v.y, (bf16_t)v.z, (bf16_t)v.w };
    *(bf16x4*)&Xl[t * XLD + q4 * 4] = pk;
  }

  const int wc = wave & 3;             // phase-Y c-block (3 tiles each)
  const int wt = wave >> 2;            // phase-Y t-block (2 tiles each)
  f32x4 yacc[3][2] = {};               // persistent output accumulators

  for (int h = 0; h < NH; ++h) {
    __syncthreads();
    // ---- Phase T (all 8 waves): T[i][c'] = sum_c X[i,c] Gt[c',c] (+w1)
    // wave owns 3 c'-tiles x 2 i-tiles; weight A-frags are coalesced 1KB loads.
    {
      const bf16_t* gt = wts;
      const int wm = (wave & 3) * 3, wn = (wave >> 2) * 2;
      f32x4 acc[3][2] = {};
#pragma unroll
      for (int ks = 0; ks < 6; ++ks) {
        bf16x8 af[3], bfr[2];
#pragma unroll
        for (int mi = 0; mi < 3; ++mi)
          af[mi] = *(const bf16x8*)&gt[((((h * 12 + wm + mi) * 6 + ks) << 6) + lane) * 8];
#pragma unroll
        for (int ni = 0; ni < 2; ++ni)
          bfr[ni] = *(const bf16x8*)&Xl[((wn + ni) * 16 + l15) * XLD + ks * 32 + lg * 8];
#pragma unroll
        for (int mi = 0; mi < 3; ++mi)
#pragma unroll
          for (int ni = 0; ni < 2; ++ni)
            acc[mi][ni] = __builtin_amdgcn_mfma_f32_16x16x32_bf16(af[mi], bfr[ni], acc[mi][ni], 0, 0, 0);
      }
      const float* w1h = w1 + h * CH;
#pragma unroll
      for (int mi = 0; mi < 3; ++mi) {
        int cp0 = (wm + mi) * 16 + lg * 4;
        const f32x4 ww = *(const f32x4*)&w1h[cp0];
#pragma unroll
        for (int ni = 0; ni < 2; ++ni) {
          int i = (wn + ni) * 16 + l15;
          if (i < 49) {
            bf16x4 pk = { (bf16_t)(acc[mi][ni][0] + ww[0]), (bf16_t)(acc[mi][ni][1] + ww[1]),
                          (bf16_t)(acc[mi][ni][2] + ww[2]), (bf16_t)(acc[mi][ni][3] + ww[3]) };
            *(bf16x4*)&Tl[i * XLD + cp0] = pk;
          }
        }
      }
    }
    __syncthreads();
    // ---- Phase S/VO: waves 0-3: scores + in-register softmax + 1 VO c-tile;
    //                  waves 4-7: 2 VO c-tiles each. U A-frags coalesced.
    bf16x4 psave[4];
    f32x4 vacc[2][4] = {};
    const bf16_t* U_w = wts + U_OFF_ELEMS;
    if (wave < 4) {
      const int it = wave, ct = 8 + wave;
      f32x4 sacc[4] = {};
#pragma unroll
      for (int ks = 0; ks < 6; ++ks) {
        bf16x8 af[4];
#pragma unroll
        for (int mi = 0; mi < 4; ++mi)
          af[mi] = *(const bf16x8*)&Xl[(mi * 16 + l15) * XLD + ks * 32 + lg * 8];
        bf16x8 bt = *(const bf16x8*)&Tl[(it * 16 + l15) * XLD + ks * 32 + lg * 8];
        bf16x8 bu8 = *(const bf16x8*)&U_w[((((h * 12 + ct) * 6 + ks) << 6) + lane) * 8];
#pragma unroll
        for (int mj = 0; mj < 4; ++mj)
          sacc[mj] = __builtin_amdgcn_mfma_f32_16x16x32_bf16(af[mj], bt, sacc[mj], 0, 0, 0);
#pragma unroll
        for (int mi = 0; mi < 4; ++mi)
          vacc[0][mi] = __builtin_amdgcn_mfma_f32_16x16x32_bf16(af[mi], bu8, vacc[0][mi], 0, 0, 0);
      }
      const float scale = 0.07216878364870322f;  // 1/sqrt(192)
      float mx = -1e30f;
#pragma unroll
      for (int mj = 0; mj < 4; ++mj)
#pragma unroll
        for (int r = 0; r < 4; ++r) {
          int j = mj * 16 + lg * 4 + r;
          if (j < 49) mx = fmaxf(mx, sacc[mj][r]);
        }
      mx = fmaxf(mx, __shfl_xor(mx, 16));
      mx = fmaxf(mx, __shfl_xor(mx, 32));
      float p[4][4];
      float sum = 0.f;
#pragma unroll
      for (int mj = 0; mj < 4; ++mj)
#pragma unroll
        for (int r = 0; r < 4; ++r) {
          int j = mj * 16 + lg * 4 + r;
          float e = (j < 49) ? __expf((sacc[mj][r] - mx) * scale) : 0.f;
          p[mj][r] = e;
          sum += e;
        }
      sum += __shfl_xor(sum, 16);
      sum += __shfl_xor(sum, 32);
      float inv = 1.f / sum;
#pragma unroll
      for (int mj = 0; mj < 4; ++mj) {
        bf16x4 pk = { (bf16_t)(p[mj][0] * inv), (bf16_t)(p[mj][1] * inv),
                      (bf16_t)(p[mj][2] * inv), (bf16_t)(p[mj][3] * inv) };
        psave[mj] = pk;
      }
    } else {
      const int c0 = (wave - 4) * 2;
#pragma unroll
      for (int ks = 0; ks < 6; ++ks) {
        bf16x8 af[4], bfu[2];
#pragma unroll
        for (int mi = 0; mi < 4; ++mi)
          af[mi] = *(const bf16x8*)&Xl[(mi * 16 + l15) * XLD + ks * 32 + lg * 8];
#pragma unroll
        for (int cj = 0; cj < 2; ++cj)
          bfu[cj] = *(const bf16x8*)&U_w[((((h * 12 + c0 + cj) * 6 + ks) << 6) + lane) * 8];
#pragma unroll
        for (int cj = 0; cj < 2; ++cj)
#pragma unroll
          for (int mi = 0; mi < 4; ++mi)
            vacc[cj][mi] = __builtin_amdgcn_mfma_f32_16x16x32_bf16(af[mi], bfu[cj], vacc[cj][mi], 0, 0, 0);
      }
    }
    __syncthreads();   // all T/X reads of phase S/VO drained
    // ---- Phase B2: write P and VOt into the dead T region
    const float* bu_h = bu + h * CH;
    if (wave < 4) {
      int i = wave * 16 + l15;
#pragma unroll
      for (int mj = 0; mj < 4; ++mj)
        *(bf16x4*)&Pl[i * ULD + mj * 16 + lg * 4] = psave[mj];
      int c = (8 + wave) * 16 + l15;
      float bb = bu_h[c];
#pragma unroll
      for (int mi = 0; mi < 4; ++mi) {
        int s0 = mi * 16 + lg * 4;
        bf16x4 pk = { (bf16_t)(vacc[0][mi][0] + bb), (bf16_t)(vacc[0][mi][1] + bb),
                      (bf16_t)(vacc[0][mi][2] + bb), (bf16_t)(vacc[0][mi][3] + bb) };
        *(bf16x4*)&VOtl[c * ULD + s0] = pk;
      }
    } else {
      const int c0 = (wave - 4) * 2;
#pragma unroll
      for (int cj = 0; cj < 2; ++cj) {
        int c = (c0 + cj) * 16 + l15;
        float bb = bu_h[c];
#pragma unroll
        for (int mi = 0; mi < 4; ++mi) {
          int s0 = mi * 16 + lg * 4;
          bf16x4 pk = { (bf16_t)(vacc[cj][mi][0] + bb), (bf16_t)(vacc[cj][mi][1] + bb),
                        (bf16_t)(vacc[cj][mi][2] + bb), (bf16_t)(vacc[cj][mi][3] + bb) };
          *(bf16x4*)&VOtl[c * ULD + s0] = pk;
        }
      }
    }
    __syncthreads();
    // ---- Phase Y: yacc[c,t] += sum_s VOt[c,s] P[t,s]
    {
#pragma unroll
      for (int ks = 0; ks < 2; ++ks) {
        bf16x8 af[3], bfr[2];
#pragma unroll
        for (int mi = 0; mi < 3; ++mi)
          af[mi] = *(const bf16x8*)&VOtl[((wc * 3 + mi) * 16 + l15) * ULD + ks * 32 + lg * 8];
#pragma unroll
        for (int ni = 0; ni < 2; ++ni)
          bfr[ni] = *(const bf16x8*)&Pl[((wt * 2 + ni) * 16 + l15) * ULD + ks * 32 + lg * 8];
#pragma unroll
        for (int mi = 0; mi < 3; ++mi)
#pragma unroll
          for (int ni = 0; ni < 2; ++ni)
            yacc[mi][ni] = __builtin_amdgcn_mfma_f32_16x16x32_bf16(af[mi], bfr[ni], yacc[mi][ni], 0, 0, 0);
      }
    }
  }

  // ---- epilogue: +bo, plain-reshape merge + roll(+3,+3), packed f32x4 stores
#pragma unroll
  for (int ni = 0; ni < 2; ++ni) {
    int t = (wt * 2 + ni) * 16 + l15;
    if (t < 49) {
      int pos = rem * 49 + t;
      int hp = pos / 112, wp = pos % 112;
      hp += SHIFT; if (hp >= HW) hp -= HW;
      wp += SHIFT; if (wp >= HW) wp -= HW;
      float* op = out + (((b * HW + hp) * HW) + wp) * CH;
#pragma unroll
      for (int mi = 0; mi < 3; ++mi) {
        int c0 = (wc * 3 + mi) * 16 + lg * 4;
        f32x4 v = yacc[mi][ni];
        v[0] += bo[c0]; v[1] += bo[c0 + 1]; v[2] += bo[c0 + 2]; v[3] += bo[c0 + 3];
        *(f32x4*)&op[c0] = v;
      }
    }
  }
}

extern "C" void kernel_launch(void* const* d_in, const int* in_sizes, int n_in,
                              void* d_out, int out_size, void* d_ws, size_t ws_size,
                              hipStream_t stream) {
  const float* x  = (const float*)d_in[0];
  const float* Wq = (const float*)d_in[1];
  const float* bq = (const float*)d_in[2];
  const float* Wk = (const float*)d_in[3];
  const float* Wv = (const float*)d_in[5];
  const float* bv = (const float*)d_in[6];
  const float* Wo = (const float*)d_in[7];
  const float* bo = (const float*)d_in[8];
  float* out = (float*)d_out;
  bf16_t* wts = (bf16_t*)d_ws;                        // Gt | U, swizzled
  float*  bu  = (float*)((char*)d_ws + BU_OFF_BYTES);
  float*  w1  = (float*)((char*)d_ws + W1_OFF_BYTES);

  prep_gt<<<NH * CH, CH, 0, stream>>>(Wq, Wk, wts);
  prep_u<<<NH * CH, CH, 0, stream>>>(Wv, Wo, wts + U_OFF_ELEMS);
  prep_bu<<<NH, CH, 0, stream>>>(bv, Wo, bu);
  prep_w1<<<NH, CH, 0, stream>>>(Wk, bq, w1);

  (void)hipFuncSetAttribute((const void*)swin_fused,
                            hipFuncAttributeMaxDynamicSharedMemorySize, LDS_BYTES);
  swin_fused<<<dim3(4096), dim3(512), LDS_BYTES, stream>>>(x, bo, wts, bu, w1, out);
}

// Round 9
// 601.443 us; speedup vs baseline: 2.6966x; 1.1179x over previous
//
#include <hip/hip_runtime.h>
#include <hip/hip_bf16.h>

typedef __bf16 bf16_t;
typedef __bf16 bf16x4 __attribute__((ext_vector_type(4)));
typedef __bf16 bf16x8 __attribute__((ext_vector_type(8)));
typedef float  f32x4  __attribute__((ext_vector_type(4)));

#define NH    6
#define CH    192
#define HW    112
#define SHIFT 3

// LDS strides (bf16 elems). XLD=200 -> 400B rows; ULD=72 -> 144B rows.
#define XLD 200
#define ULD 72

// Full double-buffered layout (no overlays), 1 block/CU, 150.5 KB:
#define X_OFF   0                      // [64][200]
#define T_OFF0  12800                  // [64][200] x2
#define T_OFF1  25600
#define VOT_OFF0 38400                 // [192][72] x2
#define VOT_OFF1 52224
#define P_OFF0  66048                  // [64][72] x2
#define P_OFF1  70656
#define LDS_ELEMS 75264
#define LDS_BYTES (LDS_ELEMS * 2)      // 150528 B

// ws: Gt swizzled (NH*CH*CH bf16) | U swizzled (NH*CH*CH bf16) | bu | w1
// Swizzled fragment layout: [h][tile(12)][ks(6)][lane(64)][e(8)] so one wave
// A-fragment load = contiguous 1024 B.
#define U_OFF_ELEMS  (NH * CH * CH)
#define BU_OFF_BYTES (2 * NH * CH * CH * 2)
#define W1_OFF_BYTES (BU_OFF_BYTES + NH * CH * 4)

// ---- prep: Gt[h][c'][c] = sum_d Wk[c',h,d] * Wq[c,h,d], written SWIZZLED ---
__global__ void prep_gt(const float* __restrict__ Wq, const float* __restrict__ Wk,
                        bf16_t* __restrict__ gt) {
  __shared__ float wk_row[CH];
  int h = blockIdx.x / CH, cp = blockIdx.x % CH;
  int c = threadIdx.x;
  wk_row[c] = Wk[(cp * NH + h) * CH + c];
  __syncthreads();
  float acc = 0.f;
  for (int d = 0; d < CH; ++d)
    acc += wk_row[d] * Wq[(c * NH + h) * CH + d];
  int tile = cp >> 4, l15 = cp & 15;
  int ks = c >> 5, lg = (c >> 3) & 3, e = c & 7;
  gt[((((h * 12 + tile) * 6 + ks) << 6) + lg * 16 + l15) * 8 + e] = (bf16_t)acc;
}

// ---- prep: U^h = Wv^h x Wo^h, rows c_out, cols c_in, written SWIZZLED ------
__global__ void prep_u(const float* __restrict__ Wv, const float* __restrict__ Wo,
                       bf16_t* __restrict__ u_out) {
  __shared__ float wv_row[CH];
  int h = blockIdx.x / CH, ci = blockIdx.x % CH;
  int t = threadIdx.x;                            // c_out
  wv_row[t] = Wv[(ci * NH + h) * CH + t];
  __syncthreads();
  float acc = 0.f;
  for (int d = 0; d < CH; ++d)
    acc += wv_row[d] * Wo[(h * CH + d) * CH + t];
  int tile = t >> 4, l15 = t & 15;
  int ks = ci >> 5, lg = (ci >> 3) & 3, e = ci & 7;
  u_out[((((h * 12 + tile) * 6 + ks) << 6) + lg * 16 + l15) * 8 + e] = (bf16_t)acc;
}

// ---- prep: bu^h = bv^h x Wo^h ---------------------------------------------
__global__ void prep_bu(const float* __restrict__ bv, const float* __restrict__ Wo,
                        float* __restrict__ bu) {
  int h = blockIdx.x, c = threadIdx.x;
  float acc = 0.f;
  for (int d = 0; d < CH; ++d)
    acc += bv[h * CH + d] * Wo[(h * CH + d) * CH + c];
  bu[h * CH + c] = acc;
}

// ---- prep: w1^h[c'] = sum_d Wk[c',h,d] * bq[h,d] ---------------------------
__global__ void prep_w1(const float* __restrict__ Wk, const float* __restrict__ bq,
                        float* __restrict__ w1) {
  int h = blockIdx.x, cp = threadIdx.x;
  float acc = 0.f;
  for (int d = 0; d < CH; ++d)
    acc += Wk[(cp * NH + h) * CH + d] * bq[h * CH + d];
  w1[h * CH + cp] = acc;
}

// ---- fused swin block: one workgroup per 7x7 window, 8 waves, 1 barrier/head
__global__ __launch_bounds__(512) void swin_fused(
    const float* __restrict__ x,
    const float* __restrict__ bo,
    const bf16_t* __restrict__ wts,     // Gt | U (both swizzled)
    const float* __restrict__ bu, const float* __restrict__ w1,
    float* __restrict__ out) {
  extern __shared__ char smem_raw[];
  bf16_t* lds = (bf16_t*)smem_raw;
  bf16_t* Xl  = lds + X_OFF;
  bf16_t* Tb[2]  = { lds + T_OFF0,   lds + T_OFF1 };
  bf16_t* VOb[2] = { lds + VOT_OFF0, lds + VOT_OFF1 };
  bf16_t* Pb[2]  = { lds + P_OFF0,   lds + P_OFF1 };

  const int tid  = threadIdx.x;
  const int wave = tid >> 6;           // 0..7
  const int lane = tid & 63;
  const int l15  = lane & 15;
  const int lg   = lane >> 4;          // 0..3

  const int blk = blockIdx.x;
  const int b   = blk >> 8;
  const int rem = blk & 255;
  const int wi  = rem >> 4, wj = rem & 15;

  // zero pad rows 49..63 of X and both T buffers
  for (int idx = tid; idx < 15 * 100; idx += 512) {
    int row = 49 + idx / 100, c2 = (idx % 100) * 2;
    *(unsigned int*)&Xl[row * XLD + c2] = 0u;
    *(unsigned int*)&Tb[0][row * XLD + c2] = 0u;
    *(unsigned int*)&Tb[1][row * XLD + c2] = 0u;
  }
  // stage window tokens (roll -3,-3 folded into the gather), f32 -> bf16
  for (int idx = tid; idx < 49 * 48; idx += 512) {
    int t = idx / 48, q4 = idx % 48;
    int hs = wi * 7 + t / 7 + SHIFT; if (hs >= HW) hs -= HW;
    int ws2 = wj * 7 + t % 7 + SHIFT; if (ws2 >= HW) ws2 -= HW;
    const float4 v = *(const float4*)&x[(((b * HW + hs) * HW) + ws2) * CH + q4 * 4];
    bf16x4 pk = { (bf16_t)v.x, (bf16_t)v.y, (bf16_t)v.z, (bf16_t)v.w };
    *(bf16x4*)&Xl[t * XLD + q4 * 4] = pk;
  }
  __syncthreads();

  const int wm = (wave & 3) * 3;       // T-phase c'-block (3 tiles)
  const int wn = (wave >> 2) * 2;      // T-phase i-tile base (2 tiles)
  const int wc = wave & 3;             // Y c-block (3 tiles)
  const int wt = wave >> 2;            // Y t-half (2 tiles)
  const float scale = 0.07216878364870322f;  // 1/sqrt(192)
  f32x4 yacc[3][2] = {};               // persistent output accumulators

  // ---- prologue: T(0) into buffer 0
  {
    const bf16_t* gt = wts;
    f32x4 acc[3][2] = {};
#pragma unroll
    for (int ks = 0; ks < 6; ++ks) {
      bf16x8 af[3], bfr[2];
#pragma unroll
      for (int mi = 0; mi < 3; ++mi)
        af[mi] = *(const bf16x8*)&gt[((((0 * 12 + wm + mi) * 6 + ks) << 6) + lane) * 8];
#pragma unroll
      for (int ni = 0; ni < 2; ++ni)
        bfr[ni] = *(const bf16x8*)&Xl[((wn + ni) * 16 + l15) * XLD + ks * 32 + lg * 8];
#pragma unroll
      for (int mi = 0; mi < 3; ++mi)
#pragma unroll
        for (int ni = 0; ni < 2; ++ni)
          acc[mi][ni] = __builtin_amdgcn_mfma_f32_16x16x32_bf16(af[mi], bfr[ni], acc[mi][ni], 0, 0, 0);
    }
    const float* w1h = w1;
#pragma unroll
    for (int mi = 0; mi < 3; ++mi) {
      int cp0 = (wm + mi) * 16 + lg * 4;
      const f32x4 ww = *(const f32x4*)&w1h[cp0];
#pragma unroll
      for (int ni = 0; ni < 2; ++ni) {
        int i = (wn + ni) * 16 + l15;
        if (i < 49) {
          bf16x4 pk = { (bf16_t)(acc[mi][ni][0] + ww[0]), (bf16_t)(acc[mi][ni][1] + ww[1]),
                        (bf16_t)(acc[mi][ni][2] + ww[2]), (bf16_t)(acc[mi][ni][3] + ww[3]) };
          *(bf16x4*)&Tb[0][i * XLD + cp0] = pk;
        }
      }
    }
  }
  __syncthreads();

  // ---- main loop: ONE barrier per head.
  // Phase(h) = S/VO(h) [reads T(h), X, U(h); writes P(h), VOt(h)]
  //          + T(h+1)  [reads X, Gt(h+1); writes T(h+1) buffer]
  //          + Y(h-1)  [reads P(h-1), VOt(h-1); accumulates yacc]
  for (int h = 0; h < NH; ++h) {
    const int cur = h & 1, nxt = (h + 1) & 1;   // nxt == prev parity
    bf16_t* Tcur = Tb[cur];
    bf16_t* Pcur = Pb[cur];
    bf16_t* VOcur = VOb[cur];

    // -- S/VO(h)
    const bf16_t* U_w = wts + U_OFF_ELEMS;
    const float* bu_h = bu + h * CH;
    if (wave < 4) {
      const int it = wave, ct = 8 + wave;
      f32x4 sacc[4] = {};
      f32x4 vacc[4] = {};
#pragma unroll
      for (int ks = 0; ks < 6; ++ks) {
        bf16x8 af[4];
#pragma unroll
        for (int mi = 0; mi < 4; ++mi)
          af[mi] = *(const bf16x8*)&Xl[(mi * 16 + l15) * XLD + ks * 32 + lg * 8];
        bf16x8 bt = *(const bf16x8*)&Tcur[(it * 16 + l15) * XLD + ks * 32 + lg * 8];
        bf16x8 bu8 = *(const bf16x8*)&U_w[((((h * 12 + ct) * 6 + ks) << 6) + lane) * 8];
#pragma unroll
        for (int mj = 0; mj < 4; ++mj)
          sacc[mj] = __builtin_amdgcn_mfma_f32_16x16x32_bf16(af[mj], bt, sacc[mj], 0, 0, 0);
#pragma unroll
        for (int mi = 0; mi < 4; ++mi)
          vacc[mi] = __builtin_amdgcn_mfma_f32_16x16x32_bf16(af[mi], bu8, vacc[mi], 0, 0, 0);
      }
      float mx = -1e30f;
#pragma unroll
      for (int mj = 0; mj < 4; ++mj)
#pragma unroll
        for (int r = 0; r < 4; ++r) {
          int j = mj * 16 + lg * 4 + r;
          if (j < 49) mx = fmaxf(mx, sacc[mj][r]);
        }
      mx = fmaxf(mx, __shfl_xor(mx, 16));
      mx = fmaxf(mx, __shfl_xor(mx, 32));
      float p[4][4];
      float sum = 0.f;
#pragma unroll
      for (int mj = 0; mj < 4; ++mj)
#pragma unroll
        for (int r = 0; r < 4; ++r) {
          int j = mj * 16 + lg * 4 + r;
          float e = (j < 49) ? __expf((sacc[mj][r] - mx) * scale) : 0.f;
          p[mj][r] = e;
          sum += e;
        }
      sum += __shfl_xor(sum, 16);
      sum += __shfl_xor(sum, 32);
      float inv = 1.f / sum;
      int i = it * 16 + l15;
#pragma unroll
      for (int mj = 0; mj < 4; ++mj) {
        bf16x4 pk = { (bf16_t)(p[mj][0] * inv), (bf16_t)(p[mj][1] * inv),
                      (bf16_t)(p[mj][2] * inv), (bf16_t)(p[mj][3] * inv) };
        *(bf16x4*)&Pcur[i * ULD + mj * 16 + lg * 4] = pk;
      }
      int c = ct * 16 + l15;
      float bb = bu_h[c];
#pragma unroll
      for (int mi = 0; mi < 4; ++mi) {
        int s0 = mi * 16 + lg * 4;
        bf16x4 pk = { (bf16_t)(vacc[mi][0] + bb), (bf16_t)(vacc[mi][1] + bb),
                      (bf16_t)(vacc[mi][2] + bb), (bf16_t)(vacc[mi][3] + bb) };
        *(bf16x4*)&VOcur[c * ULD + s0] = pk;
      }
    } else {
      const int c0 = (wave - 4) * 2;
      f32x4 vacc[2][4] = {};
#pragma unroll
      for (int ks = 0; ks < 6; ++ks) {
        bf16x8 af[4], bfu[2];
#pragma unroll
        for (int mi = 0; mi < 4; ++mi)
          af[mi] = *(const bf16x8*)&Xl[(mi * 16 + l15) * XLD + ks * 32 + lg * 8];
#pragma unroll
        for (int cj = 0; cj < 2; ++cj)
          bfu[cj] = *(const bf16x8*)&U_w[((((h * 12 + c0 + cj) * 6 + ks) << 6) + lane) * 8];
#pragma unroll
        for (int cj = 0; cj < 2; ++cj)
#pragma unroll
          for (int mi = 0; mi < 4; ++mi)
            vacc[cj][mi] = __builtin_amdgcn_mfma_f32_16x16x32_bf16(af[mi], bfu[cj], vacc[cj][mi], 0, 0, 0);
      }
#pragma unroll
      for (int cj = 0; cj < 2; ++cj) {
        int c = (c0 + cj) * 16 + l15;
        float bb = bu_h[c];
#pragma unroll
        for (int mi = 0; mi < 4; ++mi) {
          int s0 = mi * 16 + lg * 4;
          bf16x4 pk = { (bf16_t)(vacc[cj][mi][0] + bb), (bf16_t)(vacc[cj][mi][1] + bb),
                        (bf16_t)(vacc[cj][mi][2] + bb), (bf16_t)(vacc[cj][mi][3] + bb) };
          *(bf16x4*)&VOcur[c * ULD + s0] = pk;
        }
      }
    }

    // -- T(h+1) into the other buffer
    if (h < NH - 1) {
      const bf16_t* gt = wts;
      const int hn = h + 1;
      f32x4 acc[3][2] = {};
#pragma unroll
      for (int ks = 0; ks < 6; ++ks) {
        bf16x8 af[3], bfr[2];
#pragma unroll
        for (int mi = 0; mi < 3; ++mi)
          af[mi] = *(const bf16x8*)&gt[((((hn * 12 + wm + mi) * 6 + ks) << 6) + lane) * 8];
#pragma unroll
        for (int ni = 0; ni < 2; ++ni)
          bfr[ni] = *(const bf16x8*)&Xl[((wn + ni) * 16 + l15) * XLD + ks * 32 + lg * 8];
#pragma unroll
        for (int mi = 0; mi < 3; ++mi)
#pragma unroll
          for (int ni = 0; ni < 2; ++ni)
            acc[mi][ni] = __builtin_amdgcn_mfma_f32_16x16x32_bf16(af[mi], bfr[ni], acc[mi][ni], 0, 0, 0);
      }
      const float* w1h = w1 + hn * CH;
#pragma unroll
      for (int mi = 0; mi < 3; ++mi) {
        int cp0 = (wm + mi) * 16 + lg * 4;
        const f32x4 ww = *(const f32x4*)&w1h[cp0];
#pragma unroll
        for (int ni = 0; ni < 2; ++ni) {
          int i = (wn + ni) * 16 + l15;
          if (i < 49) {
            bf16x4 pk = { (bf16_t)(acc[mi][ni][0] + ww[0]), (bf16_t)(acc[mi][ni][1] + ww[1]),
                          (bf16_t)(acc[mi][ni][2] + ww[2]), (bf16_t)(acc[mi][ni][3] + ww[3]) };
            *(bf16x4*)&Tb[nxt][i * XLD + cp0] = pk;
          }
        }
      }
    }

    // -- Y(h-1) from the previous parity buffers
    if (h > 0) {
      bf16_t* Pprev  = Pb[nxt];
      bf16_t* VOprev = VOb[nxt];
#pragma unroll
      for (int ks = 0; ks < 2; ++ks) {
        bf16x8 af[3], bfr[2];
#pragma unroll
        for (int mi = 0; mi < 3; ++mi)
          af[mi] = *(const bf16x8*)&VOprev[((wc * 3 + mi) * 16 + l15) * ULD + ks * 32 + lg * 8];
#pragma unroll
        for (int ni = 0; ni < 2; ++ni)
          bfr[ni] = *(const bf16x8*)&Pprev[((wt * 2 + ni) * 16 + l15) * ULD + ks * 32 + lg * 8];
#pragma unroll
        for (int mi = 0; mi < 3; ++mi)
#pragma unroll
          for (int ni = 0; ni < 2; ++ni)
            yacc[mi][ni] = __builtin_amdgcn_mfma_f32_16x16x32_bf16(af[mi], bfr[ni], yacc[mi][ni], 0, 0, 0);
      }
    }
    __syncthreads();
  }

  // ---- tail: Y(NH-1) from parity (NH-1)&1 = 1
  {
    bf16_t* Pprev  = Pb[(NH - 1) & 1];
    bf16_t* VOprev = VOb[(NH - 1) & 1];
#pragma unroll
    for (int ks = 0; ks < 2; ++ks) {
      bf16x8 af[3], bfr[2];
#pragma unroll
      for (int mi = 0; mi < 3; ++mi)
        af[mi] = *(const bf16x8*)&VOprev[((wc * 3 + mi) * 16 + l15) * ULD + ks * 32 + lg * 8];
#pragma unroll
      for (int ni = 0; ni < 2; ++ni)
        bfr[ni] = *(const bf16x8*)&Pprev[((wt * 2 + ni) * 16 + l15) * ULD + ks * 32 + lg * 8];
#pragma unroll
      for (int mi = 0; mi < 3; ++mi)
#pragma unroll
        for (int ni = 0; ni < 2; ++ni)
          yacc[mi][ni] = __builtin_amdgcn_mfma_f32_16x16x32_bf16(af[mi], bfr[ni], yacc[mi][ni], 0, 0, 0);
    }
  }

  // ---- epilogue: +bo, plain-reshape merge + roll(+3,+3), packed f32x4 stores
#pragma unroll
  for (int ni = 0; ni < 2; ++ni) {
    int t = (wt * 2 + ni) * 16 + l15;
    if (t < 49) {
      int pos = rem * 49 + t;
      int hp = pos / 112, wp = pos % 112;
      hp += SHIFT; if (hp >= HW) hp -= HW;
      wp += SHIFT; if (wp >= HW) wp -= HW;
      float* op = out + (((b * HW + hp) * HW) + wp) * CH;
#pragma unroll
      for (int mi = 0; mi < 3; ++mi) {
        int c0 = (wc * 3 + mi) * 16 + lg * 4;
        f32x4 v = yacc[mi][ni];
        v[0] += bo[c0]; v[1] += bo[c0 + 1]; v[2] += bo[c0 + 2]; v[3] += bo[c0 + 3];
        *(f32x4*)&op[c0] = v;
      }
    }
  }
}

extern "C" void kernel_launch(void* const* d_in, const int* in_sizes, int n_in,
                              void* d_out, int out_size, void* d_ws, size_t ws_size,
                              hipStream_t stream) {
  const float* x  = (const float*)d_in[0];
  const float* Wq = (const float*)d_in[1];
  const float* bq = (const float*)d_in[2];
  const float* Wk = (const float*)d_in[3];
  const float* Wv = (const float*)d_in[5];
  const float* bv = (const float*)d_in[6];
  const float* Wo = (const float*)d_in[7];
  const float* bo = (const float*)d_in[8];
  float* out = (float*)d_out;
  bf16_t* wts = (bf16_t*)d_ws;                        // Gt | U, swizzled
  float*  bu  = (float*)((char*)d_ws + BU_OFF_BYTES);
  float*  w1  = (float*)((char*)d_ws + W1_OFF_BYTES);

  prep_gt<<<NH * CH, CH, 0, stream>>>(Wq, Wk, wts);
  prep_u<<<NH * CH, CH, 0, stream>>>(Wv, Wo, wts + U_OFF_ELEMS);
  prep_bu<<<NH, CH, 0, stream>>>(bv, Wo, bu);
  prep_w1<<<NH, CH, 0, stream>>>(Wk, bq, w1);

  (void)hipFuncSetAttribute((const void*)swin_fused,
                            hipFuncAttributeMaxDynamicSharedMemorySize, LDS_BYTES);
  swin_fused<<<dim3(4096), dim3(512), LDS_BYTES, stream>>>(x, bo, wts, bu, w1, out);
}

// Round 10
// 473.263 us; speedup vs baseline: 3.4270x; 1.2708x over previous
//
#include <hip/hip_runtime.h>
#include <hip/hip_bf16.h>

typedef __bf16 bf16_t;
typedef __bf16 bf16x4 __attribute__((ext_vector_type(4)));
typedef __bf16 bf16x8 __attribute__((ext_vector_type(8)));
typedef float  f32x4  __attribute__((ext_vector_type(4)));

#define NH    6
#define CH    192
#define HW    112
#define SHIFT 3

// LDS strides (bf16 elems). XLD=200 -> 400B rows; ULD=72 -> 144B rows.
#define XLD 200
#define ULD 72

// Overlay layout (R8-proven): 62,464 B -> two 256-thr blocks per CU.
#define X_OFF   0                     // [64][200]
#define T_OFF   (64 * XLD)            // [64][200]
#define P_OFF   T_OFF                 // overlay after S/VO read-drain barrier
#define VOT_OFF (T_OFF + 64 * ULD)    // [192][72], tail past T region
#define LDS_ELEMS (VOT_OFF + 192 * ULD)  // 31232
#define LDS_BYTES (LDS_ELEMS * 2)        // 62464 B

// ws: Gt swizzled (NH*CH*CH bf16) | U swizzled (NH*CH*CH bf16) | bu | w1
// Swizzled fragment layout: [h][tile(12)][ks(6)][lane(64)][e(8)] so one wave
// A-fragment load = contiguous 1024 B.
#define U_OFF_ELEMS  (NH * CH * CH)
#define BU_OFF_BYTES (2 * NH * CH * CH * 2)
#define W1_OFF_BYTES (BU_OFF_BYTES + NH * CH * 4)

// ---- prep: Gt[h][c'][c] = sum_d Wk[c',h,d] * Wq[c,h,d], written SWIZZLED ---
__global__ void prep_gt(const float* __restrict__ Wq, const float* __restrict__ Wk,
                        bf16_t* __restrict__ gt) {
  __shared__ float wk_row[CH];
  int h = blockIdx.x / CH, cp = blockIdx.x % CH;
  int c = threadIdx.x;
  wk_row[c] = Wk[(cp * NH + h) * CH + c];
  __syncthreads();
  float acc = 0.f;
  for (int d = 0; d < CH; ++d)
    acc += wk_row[d] * Wq[(c * NH + h) * CH + d];
  int tile = cp >> 4, l15 = cp & 15;
  int ks = c >> 5, lg = (c >> 3) & 3, e = c & 7;
  gt[((((h * 12 + tile) * 6 + ks) << 6) + lg * 16 + l15) * 8 + e] = (bf16_t)acc;
}

// ---- prep: U^h = Wv^h x Wo^h, rows c_out, cols c_in, written SWIZZLED ------
__global__ void prep_u(const float* __restrict__ Wv, const float* __restrict__ Wo,
                       bf16_t* __restrict__ u_out) {
  __shared__ float wv_row[CH];
  int h = blockIdx.x / CH, ci = blockIdx.x % CH;
  int t = threadIdx.x;                            // c_out
  wv_row[t] = Wv[(ci * NH + h) * CH + t];
  __syncthreads();
  float acc = 0.f;
  for (int d = 0; d < CH; ++d)
    acc += wv_row[d] * Wo[(h * CH + d) * CH + t];
  int tile = t >> 4, l15 = t & 15;
  int ks = ci >> 5, lg = (ci >> 3) & 3, e = ci & 7;
  u_out[((((h * 12 + tile) * 6 + ks) << 6) + lg * 16 + l15) * 8 + e] = (bf16_t)acc;
}

// ---- prep: bu^h = bv^h x Wo^h ---------------------------------------------
__global__ void prep_bu(const float* __restrict__ bv, const float* __restrict__ Wo,
                        float* __restrict__ bu) {
  int h = blockIdx.x, c = threadIdx.x;
  float acc = 0.f;
  for (int d = 0; d < CH; ++d)
    acc += bv[h * CH + d] * Wo[(h * CH + d) * CH + c];
  bu[h * CH + c] = acc;
}

// ---- prep: w1^h[c'] = sum_d Wk[c',h,d] * bq[h,d] ---------------------------
__global__ void prep_w1(const float* __restrict__ Wk, const float* __restrict__ bq,
                        float* __restrict__ w1) {
  int h = blockIdx.x, cp = threadIdx.x;
  float acc = 0.f;
  for (int d = 0; d < CH; ++d)
    acc += Wk[(cp * NH + h) * CH + d] * bq[h * CH + d];
  w1[h * CH + cp] = acc;
}

// ---- fused swin block: one 4-wave workgroup per 7x7 window, 2 blocks/CU ----
__global__ __launch_bounds__(256, 2) void swin_fused(
    const float* __restrict__ x,
    const float* __restrict__ bo,
    const bf16_t* __restrict__ wts,     // Gt | U (both swizzled)
    const float* __restrict__ bu, const float* __restrict__ w1,
    float* __restrict__ out) {
  extern __shared__ char smem_raw[];
  bf16_t* lds  = (bf16_t*)smem_raw;
  bf16_t* Xl   = lds + X_OFF;
  bf16_t* Tl   = lds + T_OFF;
  bf16_t* Pl   = lds + P_OFF;     // overlay (valid after B2)
  bf16_t* VOtl = lds + VOT_OFF;   // overlay (valid after B2)

  const int tid  = threadIdx.x;
  const int wave = tid >> 6;           // 0..3
  const int lane = tid & 63;
  const int l15  = lane & 15;
  const int lg   = lane >> 4;          // 0..3

  const int blk = blockIdx.x;
  const int b   = blk >> 8;
  const int rem = blk & 255;
  const int wi  = rem >> 4, wj = rem & 15;

  // zero pad rows 49..63 of X
  for (int idx = tid; idx < 15 * 100; idx += 256) {
    int row = 49 + idx / 100, c2 = (idx % 100) * 2;
    *(unsigned int*)&Xl[row * XLD + c2] = 0u;
  }
  // stage window tokens (roll -3,-3 folded into the gather), f32 -> bf16
  for (int idx = tid; idx < 49 * 48; idx += 256) {
    int t = idx / 48, q4 = idx % 48;
    int hs = wi * 7 + t / 7 + SHIFT; if (hs >= HW) hs -= HW;
    int ws2 = wj * 7 + t % 7 + SHIFT; if (ws2 >= HW) ws2 -= HW;
    const float4 v = *(const float4*)&x[(((b * HW + hs) * HW) + ws2) * CH + q4 * 4];
    bf16x4 pk = { (bf16_t)v.x, (bf16_t)v.y, (bf16_t)v.z, (bf16_t)v.w };
    *(bf16x4*)&Xl[t * XLD + q4 * 4] = pk;
  }

  const int wm = wave * 3;             // 3 c'-/c-tiles owned per wave
  const float scale = 0.07216878364870322f;  // 1/sqrt(192)
  f32x4 yacc[3][4] = {};               // persistent output accumulators

  for (int h = 0; h < NH; ++h) {
    __syncthreads();   // Y(h-1)/P/VOt reads drained before T(h) overwrites
    // ---- Phase T: T[i][c'] = sum_c X[i,c] Gt[c',c] (+w1)
    // wave owns c'-tiles wm..wm+2 x ALL 4 i-tiles; weight A-frags = 1KB loads.
    {
      const bf16_t* gt = wts;
      f32x4 acc[3][4] = {};
#pragma unroll
      for (int ks = 0; ks < 6; ++ks) {
        bf16x8 af[3], bfr[4];
#pragma unroll
        for (int mi = 0; mi < 3; ++mi)
          af[mi] = *(const bf16x8*)&gt[((((h * 12 + wm + mi) * 6 + ks) << 6) + lane) * 8];
#pragma unroll
        for (int ni = 0; ni < 4; ++ni)
          bfr[ni] = *(const bf16x8*)&Xl[(ni * 16 + l15) * XLD + ks * 32 + lg * 8];
#pragma unroll
        for (int mi = 0; mi < 3; ++mi)
#pragma unroll
          for (int ni = 0; ni < 4; ++ni)
            acc[mi][ni] = __builtin_amdgcn_mfma_f32_16x16x32_bf16(af[mi], bfr[ni], acc[mi][ni], 0, 0, 0);
      }
      const float* w1h = w1 + h * CH;
#pragma unroll
      for (int mi = 0; mi < 3; ++mi) {
        int cp0 = (wm + mi) * 16 + lg * 4;
        const f32x4 ww = *(const f32x4*)&w1h[cp0];
#pragma unroll
        for (int ni = 0; ni < 4; ++ni) {
          int i = ni * 16 + l15;
          if (i < 49) {
            bf16x4 pk = { (bf16_t)(acc[mi][ni][0] + ww[0]), (bf16_t)(acc[mi][ni][1] + ww[1]),
                          (bf16_t)(acc[mi][ni][2] + ww[2]), (bf16_t)(acc[mi][ni][3] + ww[3]) };
            *(bf16x4*)&Tl[i * XLD + cp0] = pk;
          }
        }
      }
    }
    __syncthreads();
    // ---- Phase S/VO: wave owns S i-tile `wave` + VO c-tiles wm..wm+2.
    // S[i,j] = sum_c' X[j,c'] T[i,c'];  VO[c][s] = sum_cin X[s,cin] U[c,cin].
    bf16x4 psave[4];
    f32x4 vacc[3][4] = {};
    const bf16_t* U_w = wts + U_OFF_ELEMS;
    {
      f32x4 sacc[4] = {};
#pragma unroll
      for (int ks = 0; ks < 6; ++ks) {
        bf16x8 af[4], bfu[3];
#pragma unroll
        for (int mi = 0; mi < 4; ++mi)
          af[mi] = *(const bf16x8*)&Xl[(mi * 16 + l15) * XLD + ks * 32 + lg * 8];
        bf16x8 bt = *(const bf16x8*)&Tl[(wave * 16 + l15) * XLD + ks * 32 + lg * 8];
#pragma unroll
        for (int mi = 0; mi < 3; ++mi)
          bfu[mi] = *(const bf16x8*)&U_w[((((h * 12 + wm + mi) * 6 + ks) << 6) + lane) * 8];
#pragma unroll
        for (int mj = 0; mj < 4; ++mj)
          sacc[mj] = __builtin_amdgcn_mfma_f32_16x16x32_bf16(af[mj], bt, sacc[mj], 0, 0, 0);
#pragma unroll
        for (int mi = 0; mi < 3; ++mi)
#pragma unroll
          for (int ms = 0; ms < 4; ++ms)
            vacc[mi][ms] = __builtin_amdgcn_mfma_f32_16x16x32_bf16(af[ms], bfu[mi], vacc[mi][ms], 0, 0, 0);
      }
      float mx = -1e30f;
#pragma unroll
      for (int mj = 0; mj < 4; ++mj)
#pragma unroll
        for (int r = 0; r < 4; ++r) {
          int j = mj * 16 + lg * 4 + r;
          if (j < 49) mx = fmaxf(mx, sacc[mj][r]);
        }
      mx = fmaxf(mx, __shfl_xor(mx, 16));
      mx = fmaxf(mx, __shfl_xor(mx, 32));
      float p[4][4];
      float sum = 0.f;
#pragma unroll
      for (int mj = 0; mj < 4; ++mj)
#pragma unroll
        for (int r = 0; r < 4; ++r) {
          int j = mj * 16 + lg * 4 + r;
          float e = (j < 49) ? __expf((sacc[mj][r] - mx) * scale) : 0.f;
          p[mj][r] = e;
          sum += e;
        }
      sum += __shfl_xor(sum, 16);
      sum += __shfl_xor(sum, 32);
      float inv = 1.f / sum;
#pragma unroll
      for (int mj = 0; mj < 4; ++mj) {
        bf16x4 pk = { (bf16_t)(p[mj][0] * inv), (bf16_t)(p[mj][1] * inv),
                      (bf16_t)(p[mj][2] * inv), (bf16_t)(p[mj][3] * inv) };
        psave[mj] = pk;
      }
    }
    __syncthreads();   // all T/X reads of phase S/VO drained
    // ---- Phase B2: write P and VOt into the dead T region (+tail)
    {
      const float* bu_h = bu + h * CH;
      int i = wave * 16 + l15;
#pragma unroll
      for (int mj = 0; mj < 4; ++mj)
        *(bf16x4*)&Pl[i * ULD + mj * 16 + lg * 4] = psave[mj];
#pragma unroll
      for (int mi = 0; mi < 3; ++mi) {
        int c = (wm + mi) * 16 + l15;
        float bb = bu_h[c];
#pragma unroll
        for (int ms = 0; ms < 4; ++ms) {
          int s0 = ms * 16 + lg * 4;
          bf16x4 pk = { (bf16_t)(vacc[mi][ms][0] + bb), (bf16_t)(vacc[mi][ms][1] + bb),
                        (bf16_t)(vacc[mi][ms][2] + bb), (bf16_t)(vacc[mi][ms][3] + bb) };
          *(bf16x4*)&VOtl[c * ULD + s0] = pk;
        }
      }
    }
    __syncthreads();
    // ---- Phase Y: yacc[c,t] += sum_s VOt[c,s] P[t,s]; wave: 3 c x 4 t tiles
    {
#pragma unroll
      for (int ks = 0; ks < 2; ++ks) {
        bf16x8 af[3], bfr[4];
#pragma unroll
        for (int mi = 0; mi < 3; ++mi)
          af[mi] = *(const bf16x8*)&VOtl[((wm + mi) * 16 + l15) * ULD + ks * 32 + lg * 8];
#pragma unroll
        for (int ni = 0; ni < 4; ++ni)
          bfr[ni] = *(const bf16x8*)&Pl[(ni * 16 + l15) * ULD + ks * 32 + lg * 8];
#pragma unroll
        for (int mi = 0; mi < 3; ++mi)
#pragma unroll
          for (int ni = 0; ni < 4; ++ni)
            yacc[mi][ni] = __builtin_amdgcn_mfma_f32_16x16x32_bf16(af[mi], bfr[ni], yacc[mi][ni], 0, 0, 0);
      }
    }
  }

  // ---- epilogue: +bo, plain-reshape merge + roll(+3,+3), packed f32x4 stores
#pragma unroll
  for (int ni = 0; ni < 4; ++ni) {
    int t = ni * 16 + l15;
    if (t < 49) {
      int pos = rem * 49 + t;
      int hp = pos / 112, wp = pos % 112;
      hp += SHIFT; if (hp >= HW) hp -= HW;
      wp += SHIFT; if (wp >= HW) wp -= HW;
      float* op = out + (((b * HW + hp) * HW) + wp) * CH;
#pragma unroll
      for (int mi = 0; mi < 3; ++mi) {
        int c0 = (wm + mi) * 16 + lg * 4;
        f32x4 v = yacc[mi][ni];
        v[0] += bo[c0]; v[1] += bo[c0 + 1]; v[2] += bo[c0 + 2]; v[3] += bo[c0 + 3];
        *(f32x4*)&op[c0] = v;
      }
    }
  }
}

extern "C" void kernel_launch(void* const* d_in, const int* in_sizes, int n_in,
                              void* d_out, int out_size, void* d_ws, size_t ws_size,
                              hipStream_t stream) {
  const float* x  = (const float*)d_in[0];
  const float* Wq = (const float*)d_in[1];
  const float* bq = (const float*)d_in[2];
  const float* Wk = (const float*)d_in[3];
  const float* Wv = (const float*)d_in[5];
  const float* bv = (const float*)d_in[6];
  const float* Wo = (const float*)d_in[7];
  const float* bo = (const float*)d_in[8];
  float* out = (float*)d_out;
  bf16_t* wts = (bf16_t*)d_ws;                        // Gt | U, swizzled
  float*  bu  = (float*)((char*)d_ws + BU_OFF_BYTES);
  float*  w1  = (float*)((char*)d_ws + W1_OFF_BYTES);

  prep_gt<<<NH * CH, CH, 0, stream>>>(Wq, Wk, wts);
  prep_u<<<NH * CH, CH, 0, stream>>>(Wv, Wo, wts + U_OFF_ELEMS);
  prep_bu<<<NH, CH, 0, stream>>>(bv, Wo, bu);
  prep_w1<<<NH, CH, 0, stream>>>(Wk, bq, w1);

  (void)hipFuncSetAttribute((const void*)swin_fused,
                            hipFuncAttributeMaxDynamicSharedMemorySize, LDS_BYTES);
  swin_fused<<<dim3(4096), dim3(256), LDS_BYTES, stream>>>(x, bo, wts, bu, w1, out);
}